// Round 3
// baseline (2660.251 us; speedup 1.0000x reference)
//
#include <hip/hip_runtime.h>
#include <hip/hip_bf16.h>
#include <math.h>

#define DIMC   1024
#define NHEADS 16
#define HDIM   64
#define BATCH  2
#define SEQ    2048
#define SCALE  0.125f

// [B][H][N][D] per tensor
#define BHND ((size_t)BATCH * NHEADS * SEQ * HDIM)   // 4,194,304 floats

// ---------------------------------------------------------------------------
// Tiled fp32 GEMM: C = A[M,K] @ W[K,N]  (row-major), 64x64 tile, BK=16,
// 256 threads, 4x4 per thread.
// MODE 0: scatter into qkv ws layout [3][B][H][N][D]
// MODE 1: add bias, direct store to out[M*N]
// ---------------------------------------------------------------------------
template <int MODE>
__global__ __launch_bounds__(256) void gemm_kernel(
    const float* __restrict__ A, const float* __restrict__ W,
    const float* __restrict__ bias, float* __restrict__ out,
    int M, int N, int K)
{
    __shared__ float As[16][68];   // [k][m], padded: rows 272B (16B aligned)
    __shared__ float Bs[16][68];   // [k][n]

    const int bm  = blockIdx.y * 64;
    const int bn  = blockIdx.x * 64;
    const int tid = threadIdx.x;
    const int tm  = tid >> 4;   // 0..15
    const int tn  = tid & 15;   // 0..15

    float acc[4][4] = {};

    for (int k0 = 0; k0 < K; k0 += 16) {
        // stage A tile (64 rows x 16 k), 4 elems/thread
        #pragma unroll
        for (int i = 0; i < 4; ++i) {
            int idx = tid + i * 256;          // 0..1023
            int m = idx >> 4, k = idx & 15;
            As[k][m] = A[(size_t)(bm + m) * K + k0 + k];
        }
        // stage B tile (16 k x 64 n), 4 elems/thread
        #pragma unroll
        for (int i = 0; i < 4; ++i) {
            int idx = tid + i * 256;
            int k = idx >> 6, n = idx & 63;
            Bs[k][n] = W[(size_t)(k0 + k) * N + bn + n];
        }
        __syncthreads();

        #pragma unroll
        for (int k = 0; k < 16; ++k) {
            float4 a = *(const float4*)&As[k][tm * 4];
            float4 b = *(const float4*)&Bs[k][tn * 4];
            acc[0][0] += a.x * b.x; acc[0][1] += a.x * b.y;
            acc[0][2] += a.x * b.z; acc[0][3] += a.x * b.w;
            acc[1][0] += a.y * b.x; acc[1][1] += a.y * b.y;
            acc[1][2] += a.y * b.z; acc[1][3] += a.y * b.w;
            acc[2][0] += a.z * b.x; acc[2][1] += a.z * b.y;
            acc[2][2] += a.z * b.z; acc[2][3] += a.z * b.w;
            acc[3][0] += a.w * b.x; acc[3][1] += a.w * b.y;
            acc[3][2] += a.w * b.z; acc[3][3] += a.w * b.w;
        }
        __syncthreads();
    }

    if (MODE == 0) {
        // col block is 64-aligned -> (which, head) constant per block
        const int which = bn >> 10;            // 0..2 (q/k/v)
        const int hh    = (bn & 1023) >> 6;    // head
        const int dbase = tn * 4;              // d within head
        #pragma unroll
        for (int i = 0; i < 4; ++i) {
            int row = bm + tm * 4 + i;
            int b   = row >> 11;               // /2048
            int n   = row & 2047;
            float* dst = out + (size_t)which * BHND +
                         (((size_t)b * NHEADS + hh) * SEQ + n) * HDIM + dbase;
            *(float4*)dst = make_float4(acc[i][0], acc[i][1], acc[i][2], acc[i][3]);
        }
    } else {
        const int col = bn + tn * 4;
        float4 bv = *(const float4*)&bias[col];
        #pragma unroll
        for (int i = 0; i < 4; ++i) {
            int row = bm + tm * 4 + i;
            float4 o = make_float4(acc[i][0] + bv.x, acc[i][1] + bv.y,
                                   acc[i][2] + bv.z, acc[i][3] + bv.w);
            *(float4*)&out[(size_t)row * N + col] = o;
        }
    }
}

// ---------------------------------------------------------------------------
// Flash attention, fp32. One thread per q-row. 256 q-rows per block.
// Post-softmax multiplicative key mask: denominator l uses UNMASKED exp,
// numerator accumulates exp * mask[key] * v.
// Output written as [B][N][C] (C = h*64+d) so proj GEMM reads it row-major.
// ---------------------------------------------------------------------------
__global__ __launch_bounds__(256) void attn_kernel(
    const float* __restrict__ qb, const float* __restrict__ kb,
    const float* __restrict__ vb, const float* __restrict__ mask,
    float* __restrict__ out)
{
    __shared__ float Ks[32][64];
    __shared__ float Vs[32][64];
    __shared__ float Ms[32];

    const int bid  = blockIdx.x;      // 0..255
    const int qblk = bid & 7;
    const int h    = (bid >> 3) & 15;
    const int b    = bid >> 7;
    const int tid  = threadIdx.x;
    const int row  = qblk * 256 + tid;           // q row in [0,2048)
    const size_t base = ((size_t)b * NHEADS + h) * SEQ * HDIM;

    // q row, pre-scaled
    float4 q[16];
    #pragma unroll
    for (int i = 0; i < 16; ++i) {
        float4 t = *(const float4*)&qb[base + (size_t)row * HDIM + i * 4];
        q[i] = make_float4(t.x * SCALE, t.y * SCALE, t.z * SCALE, t.w * SCALE);
    }

    float acc[64];
    #pragma unroll
    for (int d = 0; d < 64; ++d) acc[d] = 0.f;
    float m = -1e30f, l = 0.f;

    for (int k0 = 0; k0 < SEQ; k0 += 32) {
        __syncthreads();   // previous iteration's LDS reads complete
        // stage K, V (32x64 each): 2 float4 per thread per tensor
        #pragma unroll
        for (int i = 0; i < 2; ++i) {
            int idx = tid + i * 256;             // float4 slot 0..511
            int r = idx >> 4, c = (idx & 15) * 4;
            *(float4*)&Ks[r][c] = *(const float4*)&kb[base + (size_t)(k0 + r) * HDIM + c];
            *(float4*)&Vs[r][c] = *(const float4*)&vb[base + (size_t)(k0 + r) * HDIM + c];
        }
        if (tid < 32) Ms[tid] = mask[b * SEQ + k0 + tid];
        __syncthreads();

        float s[32];
        #pragma unroll
        for (int j = 0; j < 32; ++j) {
            float s0 = 0.f, s1 = 0.f, s2 = 0.f, s3 = 0.f;
            #pragma unroll
            for (int i = 0; i < 16; ++i) {
                float4 kv = *(const float4*)&Ks[j][i * 4];
                s0 += q[i].x * kv.x; s1 += q[i].y * kv.y;
                s2 += q[i].z * kv.z; s3 += q[i].w * kv.w;
            }
            s[j] = (s0 + s1) + (s2 + s3);
        }

        float bmax = s[0];
        #pragma unroll
        for (int j = 1; j < 32; ++j) bmax = fmaxf(bmax, s[j]);
        float mnew = fmaxf(m, bmax);
        float corr = __expf(m - mnew);
        l *= corr;
        #pragma unroll
        for (int d = 0; d < 64; ++d) acc[d] *= corr;
        m = mnew;

        #pragma unroll
        for (int j = 0; j < 32; ++j) {
            float p = __expf(s[j] - m);
            l += p;
            float pm = p * Ms[j];
            #pragma unroll
            for (int i = 0; i < 16; ++i) {
                float4 vv = *(const float4*)&Vs[j][i * 4];
                acc[i * 4 + 0] += pm * vv.x;
                acc[i * 4 + 1] += pm * vv.y;
                acc[i * 4 + 2] += pm * vv.z;
                acc[i * 4 + 3] += pm * vv.w;
            }
        }
    }

    const float inv = 1.f / l;
    float* dst = &out[((size_t)(b * SEQ + row)) * DIMC + h * HDIM];
    #pragma unroll
    for (int i = 0; i < 16; ++i) {
        *(float4*)&dst[i * 4] = make_float4(acc[i * 4 + 0] * inv, acc[i * 4 + 1] * inv,
                                            acc[i * 4 + 2] * inv, acc[i * 4 + 3] * inv);
    }
}

__global__ void mask_sqrt_kernel(const float* __restrict__ mask,
                                 float* __restrict__ out, int n)
{
    int i = blockIdx.x * 256 + threadIdx.x;
    if (i < n) out[i] = sqrtf(mask[i]);
}

// ---------------------------------------------------------------------------
extern "C" void kernel_launch(void* const* d_in, const int* in_sizes, int n_in,
                              void* d_out, int out_size, void* d_ws, size_t ws_size,
                              hipStream_t stream)
{
    const float* h      = (const float*)d_in[0];   // [2,2048,1024]
    const float* mask   = (const float*)d_in[1];   // [2,2048]
    const float* w_qkv  = (const float*)d_in[2];   // [1024,3072]
    const float* w_proj = (const float*)d_in[3];   // [1024,1024]
    const float* b_proj = (const float*)d_in[4];   // [1024]
    float* out = (float*)d_out;                    // [2*2048*1024] + [2*2048]
    float* ws  = (float*)d_ws;

    float* qb       = ws;                 // [B][H][N][D]
    float* kb       = ws + BHND;
    float* vb       = ws + 2 * BHND;
    float* attn_out = ws + 3 * BHND;      // [B][N][C]

    // 1) qkv projection, scattered into q/k/v [B][H][N][D]
    dim3 g1(3 * DIMC / 64, BATCH * SEQ / 64);
    gemm_kernel<0><<<g1, 256, 0, stream>>>(h, w_qkv, nullptr, ws,
                                           BATCH * SEQ, 3 * DIMC, DIMC);

    // 2) flash attention with post-softmax key mask
    attn_kernel<<<BATCH * NHEADS * (SEQ / 256), 256, 0, stream>>>(
        qb, kb, vb, mask, attn_out);

    // 3) output projection + bias
    dim3 g2(DIMC / 64, BATCH * SEQ / 64);
    gemm_kernel<1><<<g2, 256, 0, stream>>>(attn_out, w_proj, b_proj, out,
                                           BATCH * SEQ, DIMC, DIMC);

    // 4) new_mask = sqrt(mask)
    mask_sqrt_kernel<<<(BATCH * SEQ + 255) / 256, 256, 0, stream>>>(
        mask, out + (size_t)BATCH * SEQ * DIMC, BATCH * SEQ);
}

// Round 4
// 686.953 us; speedup vs baseline: 3.8725x; 3.8725x over previous
//
#include <hip/hip_runtime.h>
#include <hip/hip_bf16.h>
#include <math.h>

#define DIMC   1024
#define NHEADS 16
#define HDIM   64
#define BATCH  2
#define SEQ    2048
#define SCALE  0.125f

typedef unsigned short u16;
typedef __attribute__((ext_vector_type(8))) short bf16x8;   // 8 bf16 = 4 VGPRs
typedef __attribute__((ext_vector_type(4))) float f32x4;

// [B][H][N][D] per tensor, element count
#define BHND ((size_t)BATCH * NHEADS * SEQ * HDIM)   // 4,194,304

__device__ inline u16 f2bf(float x) {
    __hip_bfloat16 h = __float2bfloat16(x);
    return *reinterpret_cast<u16*>(&h);
}

// ---------------------------------------------------------------------------
// Tiled fp32 GEMM: C = A[M,K] @ W[K,N], 64x64 tile, BK=16, 256 thr, 4x4/thr.
// MODE 0: emit bf16 into qkv ws: q (pre-scaled by SCALE) [B][H][N][D],
//         k [B][H][N][D], v TRANSPOSED [B][H][D][N].
// MODE 1: fp32 + bias, direct store to out.
// ---------------------------------------------------------------------------
template <int MODE>
__global__ __launch_bounds__(256) void gemm_kernel(
    const float* __restrict__ A, const float* __restrict__ W,
    const float* __restrict__ bias, float* __restrict__ outf,
    u16* __restrict__ outb, int M, int N, int K)
{
    __shared__ float As[16][68];
    __shared__ float Bs[16][68];

    const int bm  = blockIdx.y * 64;
    const int bn  = blockIdx.x * 64;
    const int tid = threadIdx.x;
    const int tm  = tid >> 4;
    const int tn  = tid & 15;

    float acc[4][4] = {};

    for (int k0 = 0; k0 < K; k0 += 16) {
        #pragma unroll
        for (int i = 0; i < 4; ++i) {
            int idx = tid + i * 256;
            int m = idx >> 4, k = idx & 15;
            As[k][m] = A[(size_t)(bm + m) * K + k0 + k];
        }
        #pragma unroll
        for (int i = 0; i < 4; ++i) {
            int idx = tid + i * 256;
            int k = idx >> 6, n = idx & 63;
            Bs[k][n] = W[(size_t)(k0 + k) * N + bn + n];
        }
        __syncthreads();

        #pragma unroll
        for (int k = 0; k < 16; ++k) {
            float4 a = *(const float4*)&As[k][tm * 4];
            float4 b = *(const float4*)&Bs[k][tn * 4];
            acc[0][0] += a.x * b.x; acc[0][1] += a.x * b.y;
            acc[0][2] += a.x * b.z; acc[0][3] += a.x * b.w;
            acc[1][0] += a.y * b.x; acc[1][1] += a.y * b.y;
            acc[1][2] += a.y * b.z; acc[1][3] += a.y * b.w;
            acc[2][0] += a.z * b.x; acc[2][1] += a.z * b.y;
            acc[2][2] += a.z * b.z; acc[2][3] += a.z * b.w;
            acc[3][0] += a.w * b.x; acc[3][1] += a.w * b.y;
            acc[3][2] += a.w * b.z; acc[3][3] += a.w * b.w;
        }
        __syncthreads();
    }

    if (MODE == 0) {
        const int which = bn >> 10;            // 0=q 1=k 2=v
        const int hh    = (bn & 1023) >> 6;    // head
        const int dbase = tn * 4;
        const int bb    = bm >> 11;            // batch (64 | 2048)
        const int n0    = (bm & 2047) + tm * 4;
        const float sc  = (which == 0) ? SCALE : 1.f;
        if (which < 2) {
            u16* dst = outb + (size_t)which * BHND +
                       ((size_t)bb * NHEADS + hh) * SEQ * HDIM;
            #pragma unroll
            for (int i = 0; i < 4; ++i) {
                ushort4 o;
                o.x = f2bf(acc[i][0] * sc); o.y = f2bf(acc[i][1] * sc);
                o.z = f2bf(acc[i][2] * sc); o.w = f2bf(acc[i][3] * sc);
                *(ushort4*)&dst[(size_t)(n0 + i) * HDIM + dbase] = o;
            }
        } else {
            // v transposed: [B][H][D][N]
            u16* dst = outb + 2 * BHND +
                       ((size_t)bb * NHEADS + hh) * HDIM * SEQ;
            #pragma unroll
            for (int j = 0; j < 4; ++j) {
                ushort4 o;
                o.x = f2bf(acc[0][j]); o.y = f2bf(acc[1][j]);
                o.z = f2bf(acc[2][j]); o.w = f2bf(acc[3][j]);
                *(ushort4*)&dst[(size_t)(dbase + j) * SEQ + n0] = o;
            }
        }
    } else {
        const int col = bn + tn * 4;
        float4 bv = *(const float4*)&bias[col];
        #pragma unroll
        for (int i = 0; i < 4; ++i) {
            int row = bm + tm * 4 + i;
            float4 o = make_float4(acc[i][0] + bv.x, acc[i][1] + bv.y,
                                   acc[i][2] + bv.z, acc[i][3] + bv.w);
            *(float4*)&outf[(size_t)row * N + col] = o;
        }
    }
}

// ---------------------------------------------------------------------------
// MFMA flash attention, bf16 inputs, fp32 softmax/accum.
// Block = 4 waves, each wave owns 16 q-rows (64 q-rows/block).
// KV tile = 32 keys. S = mfma(Q,K): D layout lane: key=(l&15)+16kt,
// q=4*(l>>4)+r.  Online softmax with UNMASKED denominator; P*mask bounced
// through per-wave LDS (row stride 40 u16) into A-frag layout for PV.
// K LDS tile XOR-swizzled (G4: [32][128B] rows are 16-way conflicted raw).
// V is pre-transposed [B][H][D][N] so PV B-frags are contiguous reads.
// ---------------------------------------------------------------------------
__global__ __launch_bounds__(256) void attn_mfma_kernel(
    const u16* __restrict__ qb, const u16* __restrict__ kb,
    const u16* __restrict__ vtb, const float* __restrict__ mask,
    float* __restrict__ out)
{
    __shared__ __align__(16) u16 Ks[32 * 64];     // swizzled
    __shared__ __align__(16) u16 Vt[64 * 32];     // [d][k], linear
    __shared__ __align__(16) u16 Plds[4][16 * 40];
    __shared__ float Ms[32];

    const int bid  = blockIdx.x;          // 1024 = B*H*(SEQ/64)
    const int qt   = bid & 31;
    const int h    = (bid >> 5) & 15;
    const int b    = bid >> 9;
    const int tid  = threadIdx.x;
    const int wid  = tid >> 6;
    const int lane = tid & 63;
    const int lo   = lane & 15;
    const int g    = lane >> 4;

    const size_t bh = (size_t)b * NHEADS + h;
    const int qbase = qt * 64 + wid * 16;

    // Q A-frags: row = qbase+lo, kdim = ks*32 + 8g + j  (held all kernel)
    const u16* qrowp = qb + (bh * SEQ + qbase + lo) * HDIM + 8 * g;
    const bf16x8 aq0 = *(const bf16x8*)(qrowp);
    const bf16x8 aq1 = *(const bf16x8*)(qrowp + 32);

    // staging indices
    const int krow = tid >> 3, kseg = tid & 7;
    const int kidx = krow * 64 + ((kseg * 8) ^ ((krow & 7) << 3));
    const u16* kgp = kb + bh * SEQ * HDIM + (size_t)krow * HDIM + kseg * 8;
    const int vrow = tid >> 2, vseg = tid & 3;
    const int vidx = vrow * 32 + vseg * 8;
    const u16* vgp = vtb + (bh * HDIM + vrow) * SEQ + vseg * 8;

    // K-frag read offsets (B operand of QK): key = lo+16kt, seg = ks*32+8g
    int kf[2][2];
    #pragma unroll
    for (int kt = 0; kt < 2; ++kt) {
        int key = lo + 16 * kt;
        #pragma unroll
        for (int ks = 0; ks < 2; ++ks)
            kf[kt][ks] = key * 64 + ((ks * 32 + 8 * g) ^ ((key & 7) << 3));
    }

    f32x4 acc[4] = {};            // O[dtile][r]
    float mrun[4], lrun[4];
    #pragma unroll
    for (int r = 0; r < 4; ++r) { mrun[r] = -1e30f; lrun[r] = 0.f; }

    u16* pw = &Plds[wid][0];

    for (int k0 = 0; k0 < SEQ; k0 += 32) {
        __syncthreads();
        *(bf16x8*)&Ks[kidx] = *(const bf16x8*)(kgp + (size_t)k0 * HDIM);
        *(bf16x8*)&Vt[vidx] = *(const bf16x8*)(vgp + k0);
        if (tid < 32) Ms[tid] = mask[b * SEQ + k0 + tid];
        __syncthreads();

        // QK^T: S[16q x 32key], q pre-scaled by SCALE in the qkv GEMM
        f32x4 s0 = {}, s1 = {};
        s0 = __builtin_amdgcn_mfma_f32_16x16x32_bf16(aq0, *(const bf16x8*)&Ks[kf[0][0]], s0, 0, 0, 0);
        s0 = __builtin_amdgcn_mfma_f32_16x16x32_bf16(aq1, *(const bf16x8*)&Ks[kf[0][1]], s0, 0, 0, 0);
        s1 = __builtin_amdgcn_mfma_f32_16x16x32_bf16(aq0, *(const bf16x8*)&Ks[kf[1][0]], s1, 0, 0, 0);
        s1 = __builtin_amdgcn_mfma_f32_16x16x32_bf16(aq1, *(const bf16x8*)&Ks[kf[1][1]], s1, 0, 0, 0);

        // online softmax per q-row (rows 4g+r live across the 16-lane group)
        float p0v[4], p1v[4];
        #pragma unroll
        for (int r = 0; r < 4; ++r) {
            float rm = fmaxf(s0[r], s1[r]);
            rm = fmaxf(rm, __shfl_xor(rm, 1));
            rm = fmaxf(rm, __shfl_xor(rm, 2));
            rm = fmaxf(rm, __shfl_xor(rm, 4));
            rm = fmaxf(rm, __shfl_xor(rm, 8));
            float mnew = fmaxf(mrun[r], rm);
            float corr = __expf(mrun[r] - mnew);
            mrun[r] = mnew;
            float p0 = __expf(s0[r] - mnew);
            float p1 = __expf(s1[r] - mnew);
            float ps = p0 + p1;                 // UNMASKED denominator
            ps += __shfl_xor(ps, 1);
            ps += __shfl_xor(ps, 2);
            ps += __shfl_xor(ps, 4);
            ps += __shfl_xor(ps, 8);
            lrun[r] = lrun[r] * corr + ps;
            #pragma unroll
            for (int dt = 0; dt < 4; ++dt) acc[dt][r] *= corr;
            p0v[r] = p0; p1v[r] = p1;
        }

        // masked numerator -> P in LDS (A-frag layout for PV)
        const float mv0 = Ms[lo], mv1 = Ms[lo + 16];
        #pragma unroll
        for (int r = 0; r < 4; ++r) {
            pw[(4 * g + r) * 40 + lo]      = f2bf(p0v[r] * mv0);
            pw[(4 * g + r) * 40 + lo + 16] = f2bf(p1v[r] * mv1);
        }

        // PV: O += P[16,32] @ V[32,64]   (same-wave DS ops are in-order)
        const bf16x8 pa = *(const bf16x8*)&pw[lo * 40 + 8 * g];
        #pragma unroll
        for (int dt = 0; dt < 4; ++dt) {
            const bf16x8 bv = *(const bf16x8*)&Vt[(lo + 16 * dt) * 32 + 8 * g];
            acc[dt] = __builtin_amdgcn_mfma_f32_16x16x32_bf16(pa, bv, acc[dt], 0, 0, 0);
        }
    }

    // epilogue: out[B][N][C] fp32 for the proj GEMM
    #pragma unroll
    for (int r = 0; r < 4; ++r) {
        float inv = 1.f / lrun[r];
        size_t row = (size_t)b * SEQ + qbase + 4 * g + r;
        float* dst = out + row * DIMC + h * HDIM + lo;
        #pragma unroll
        for (int dt = 0; dt < 4; ++dt) dst[16 * dt] = acc[dt][r] * inv;
    }
}

__global__ void mask_sqrt_kernel(const float* __restrict__ mask,
                                 float* __restrict__ out, int n)
{
    int i = blockIdx.x * 256 + threadIdx.x;
    if (i < n) out[i] = sqrtf(mask[i]);
}

// ---------------------------------------------------------------------------
extern "C" void kernel_launch(void* const* d_in, const int* in_sizes, int n_in,
                              void* d_out, int out_size, void* d_ws, size_t ws_size,
                              hipStream_t stream)
{
    const float* h      = (const float*)d_in[0];   // [2,2048,1024]
    const float* mask   = (const float*)d_in[1];   // [2,2048]
    const float* w_qkv  = (const float*)d_in[2];   // [1024,3072]
    const float* w_proj = (const float*)d_in[3];   // [1024,1024]
    const float* b_proj = (const float*)d_in[4];   // [1024]
    float* out = (float*)d_out;

    u16*   qkv      = (u16*)d_ws;                        // 3*BHND bf16
    float* attn_out = (float*)((u16*)d_ws + 3 * BHND);   // [B][N][C] fp32

    // 1) qkv projection -> bf16 q(scaled)/k [B][H][N][D], v^T [B][H][D][N]
    dim3 g1(3 * DIMC / 64, BATCH * SEQ / 64);
    gemm_kernel<0><<<g1, 256, 0, stream>>>(h, w_qkv, nullptr, nullptr, qkv,
                                           BATCH * SEQ, 3 * DIMC, DIMC);

    // 2) MFMA flash attention
    attn_mfma_kernel<<<BATCH * NHEADS * (SEQ / 64), 256, 0, stream>>>(
        qkv, qkv + BHND, qkv + 2 * BHND, mask, attn_out);

    // 3) output projection + bias (fp32)
    dim3 g2(DIMC / 64, BATCH * SEQ / 64);
    gemm_kernel<1><<<g2, 256, 0, stream>>>(attn_out, w_proj, b_proj, out,
                                           nullptr, BATCH * SEQ, DIMC, DIMC);

    // 4) new_mask = sqrt(mask)
    mask_sqrt_kernel<<<(BATCH * SEQ + 255) / 256, 256, 0, stream>>>(
        mask, out + (size_t)BATCH * SEQ * DIMC, BATCH * SEQ);
}

// Round 6
// 302.367 us; speedup vs baseline: 8.7981x; 2.2719x over previous
//
#include <hip/hip_runtime.h>
#include <hip/hip_bf16.h>
#include <math.h>

#define DIMC   1024
#define NHEADS 16
#define HDIM   64
#define BATCH  2
#define SEQ    2048
#define SCALE  0.125f

typedef unsigned short u16;
typedef __attribute__((ext_vector_type(8))) short bf16x8;   // 8 bf16 = 4 VGPRs
typedef __attribute__((ext_vector_type(4))) float f32x4;

// [B][H][N][D] per tensor, element count
#define BHND ((size_t)BATCH * NHEADS * SEQ * HDIM)   // 4,194,304
#define MROWS ((size_t)BATCH * SEQ)                  // 4096

__device__ __forceinline__ u16 f2bf(float x) {
    __hip_bfloat16 h = __float2bfloat16(x);
    return *reinterpret_cast<u16*>(&h);
}
__device__ __forceinline__ float bf2f(u16 x) {
    unsigned int u = ((unsigned int)x) << 16;
    return __uint_as_float(u);
}
__device__ __forceinline__ void gload_lds16(const u16* g, u16* l) {
    __builtin_amdgcn_global_load_lds(
        (const __attribute__((address_space(1))) unsigned int*)g,
        (__attribute__((address_space(3))) unsigned int*)l, 16, 0, 0);
}

// ---------------------------------------------------------------------------
// Prepass 1: elementwise split fp32 -> bf16 hi + lo  (hi+lo ~= x to 2^-17)
// ---------------------------------------------------------------------------
__global__ __launch_bounds__(256) void splita_kernel(
    const float* __restrict__ in, u16* __restrict__ hi, u16* __restrict__ lo)
{
    int i = (blockIdx.x * 256 + threadIdx.x) * 8;
    float4 a = *(const float4*)&in[i];
    float4 b = *(const float4*)&in[i + 4];
    float v[8] = {a.x, a.y, a.z, a.w, b.x, b.y, b.z, b.w};
    bf16x8 vh, vl;
    #pragma unroll
    for (int j = 0; j < 8; ++j) {
        u16 h = f2bf(v[j]);
        vh[j] = (short)h;
        vl[j] = (short)f2bf(v[j] - bf2f(h));
    }
    *(bf16x8*)&hi[i] = vh;
    *(bf16x8*)&lo[i] = vl;
}

// ---------------------------------------------------------------------------
// Prepass 2: W [K][N] fp32 -> transposed split bf16  Thi/Tlo [N][K]
// (B-operand fragments then read contiguous along K)
// ---------------------------------------------------------------------------
__global__ __launch_bounds__(256) void splitw_kernel(
    const float* __restrict__ W, u16* __restrict__ Thi, u16* __restrict__ Tlo,
    int K, int N)
{
    __shared__ float Ws[64][65];
    const int kb  = blockIdx.x * 64;
    const int nb  = blockIdx.y * 64;
    const int tid = threadIdx.x;
    const int jr  = (tid & 15) * 4;
    const int ir  = tid >> 4;
    #pragma unroll
    for (int it = 0; it < 4; ++it) {
        int i = ir + it * 16;
        *(float4*)&Ws[i][jr] = *(const float4*)&W[(size_t)(kb + i) * N + nb + jr];
    }
    __syncthreads();
    const int n  = tid >> 2;
    const int k0 = (tid & 3) * 16;
    bf16x8 h0, h1, l0, l1;
    #pragma unroll
    for (int kk = 0; kk < 8; ++kk) {
        float x = Ws[k0 + kk][n];
        u16 h = f2bf(x);
        h0[kk] = (short)h; l0[kk] = (short)f2bf(x - bf2f(h));
        float y = Ws[k0 + 8 + kk][n];
        u16 h2 = f2bf(y);
        h1[kk] = (short)h2; l1[kk] = (short)f2bf(y - bf2f(h2));
    }
    size_t off = (size_t)(nb + n) * K + kb + k0;
    *(bf16x8*)&Thi[off]     = h0;
    *(bf16x8*)&Thi[off + 8] = h1;
    *(bf16x8*)&Tlo[off]     = l0;
    *(bf16x8*)&Tlo[off + 8] = l1;
}

// ---------------------------------------------------------------------------
// Split-bf16 MFMA GEMM: C = A @ W with A = Ahi+Alo [M][K], W^T = Bhi+Blo [N][K].
// C ≈ Ahi@Whi + Ahi@Wlo + Alo@Whi  (3 MFMAs per fragment pair, fp32-class err).
// 128x128 tile, BK=32, 256 thr = 4 waves x (64x64). global_load_lds staging.
// MODE 0: scatter bf16 q(*SCALE)/k [B][H][N][D], v^T [B][H][D][N]
// MODE 1: + bias, fp32 store to out[M][N]
// ---------------------------------------------------------------------------
template <int MODE>
__global__ __launch_bounds__(256) void gemm_split_kernel(
    const u16* __restrict__ Ahi, const u16* __restrict__ Alo,
    const u16* __restrict__ Bhi, const u16* __restrict__ Blo,
    const float* __restrict__ bias,
    float* __restrict__ outf, u16* __restrict__ outb,
    int M, int N, int K)
{
    __shared__ __align__(16) u16 lds[4][128 * 32];   // Ahi, Alo, BhiT, BloT

    const int bm   = blockIdx.y * 128;
    const int bn   = blockIdx.x * 128;
    const int tid  = threadIdx.x;
    const int wid  = tid >> 6;
    const int lane = tid & 63;
    const int lo   = lane & 15;
    const int g4   = lane >> 4;
    const int wr   = wid >> 1, wc = wid & 1;

    // staging: wave wid owns tile wid; 8 chunks of 1KB; lane -> (row, kseg)
    const int mrow = lane >> 2;
    const int ks8  = (lane & 3) * 8;
    const u16* g0;
    if      (wid == 0) g0 = Ahi + (size_t)(bm + mrow) * K + ks8;
    else if (wid == 1) g0 = Alo + (size_t)(bm + mrow) * K + ks8;
    else if (wid == 2) g0 = Bhi + (size_t)(bn + mrow) * K + ks8;
    else               g0 = Blo + (size_t)(bn + mrow) * K + ks8;
    u16* lbase = &lds[wid][0];

    f32x4 acc[4][4] = {};

    for (int k0 = 0; k0 < K; k0 += 32) {
        const u16* g = g0 + k0;
        #pragma unroll
        for (int s = 0; s < 8; ++s)
            gload_lds16(g + (size_t)s * 16 * K, lbase + s * 512);
        __syncthreads();   // compiler drains vmcnt before barrier -> LDS ready

        bf16x8 bh[4], bl[4];
        #pragma unroll
        for (int ni = 0; ni < 4; ++ni) {
            int row = wc * 64 + ni * 16 + lo;
            bh[ni] = *(const bf16x8*)&lds[2][row * 32 + g4 * 8];
            bl[ni] = *(const bf16x8*)&lds[3][row * 32 + g4 * 8];
        }
        #pragma unroll
        for (int mi = 0; mi < 4; ++mi) {
            int row = wr * 64 + mi * 16 + lo;
            bf16x8 ah = *(const bf16x8*)&lds[0][row * 32 + g4 * 8];
            bf16x8 al = *(const bf16x8*)&lds[1][row * 32 + g4 * 8];
            #pragma unroll
            for (int ni = 0; ni < 4; ++ni) {
                acc[mi][ni] = __builtin_amdgcn_mfma_f32_16x16x32_bf16(ah, bh[ni], acc[mi][ni], 0, 0, 0);
                acc[mi][ni] = __builtin_amdgcn_mfma_f32_16x16x32_bf16(ah, bl[ni], acc[mi][ni], 0, 0, 0);
                acc[mi][ni] = __builtin_amdgcn_mfma_f32_16x16x32_bf16(al, bh[ni], acc[mi][ni], 0, 0, 0);
            }
        }
        __syncthreads();
    }

    // C/D layout per frag: col = lo, row = 4*g4 + r
    if (MODE == 0) {
        #pragma unroll
        for (int mi = 0; mi < 4; ++mi) {
            int m0 = bm + wr * 64 + mi * 16 + 4 * g4;
            #pragma unroll
            for (int ni = 0; ni < 4; ++ni) {
                int n0    = bn + wc * 64 + ni * 16;
                int which = n0 >> 10;
                int head  = (n0 & 1023) >> 6;
                int d     = (n0 & 63) + lo;
                if (which == 0) {
                    #pragma unroll
                    for (int r = 0; r < 4; ++r) {
                        int m = m0 + r, b = m >> 11, seq = m & 2047;
                        outb[(((size_t)b * NHEADS + head) * SEQ + seq) * HDIM + d] =
                            f2bf(acc[mi][ni][r] * SCALE);
                    }
                } else if (which == 1) {
                    #pragma unroll
                    for (int r = 0; r < 4; ++r) {
                        int m = m0 + r, b = m >> 11, seq = m & 2047;
                        outb[BHND + (((size_t)b * NHEADS + head) * SEQ + seq) * HDIM + d] =
                            f2bf(acc[mi][ni][r]);
                    }
                } else {
                    int b = m0 >> 11, seq0 = m0 & 2047;   // r=0..3 same batch
                    ushort4 o;
                    o.x = f2bf(acc[mi][ni][0]); o.y = f2bf(acc[mi][ni][1]);
                    o.z = f2bf(acc[mi][ni][2]); o.w = f2bf(acc[mi][ni][3]);
                    *(ushort4*)&outb[2 * BHND +
                        (((size_t)b * NHEADS + head) * HDIM + d) * SEQ + seq0] = o;
                }
            }
        }
    } else {
        #pragma unroll
        for (int ni = 0; ni < 4; ++ni) {
            int col = bn + wc * 64 + ni * 16 + lo;
            float bv = bias[col];
            #pragma unroll
            for (int mi = 0; mi < 4; ++mi) {
                int m0 = bm + wr * 64 + mi * 16 + 4 * g4;
                #pragma unroll
                for (int r = 0; r < 4; ++r)
                    outf[(size_t)(m0 + r) * N + col] = acc[mi][ni][r] + bv;
            }
        }
    }
}

// ---------------------------------------------------------------------------
// MFMA flash attention (validated round 4). Epilogue now emits split bf16
// O = Ohi + Olo [B*SEQ][DIMC] to feed the split proj GEMM.
// ---------------------------------------------------------------------------
__global__ __launch_bounds__(256) void attn_mfma_kernel(
    const u16* __restrict__ qb, const u16* __restrict__ kb,
    const u16* __restrict__ vtb, const float* __restrict__ mask,
    u16* __restrict__ ohi, u16* __restrict__ olo)
{
    __shared__ __align__(16) u16 Ks[32 * 64];     // swizzled
    __shared__ __align__(16) u16 Vt[64 * 32];     // [d][k], linear
    __shared__ __align__(16) u16 Plds[4][16 * 40];
    __shared__ float Ms[32];

    const int bid  = blockIdx.x;          // 1024 = B*H*(SEQ/64)
    const int qt   = bid & 31;
    const int h    = (bid >> 5) & 15;
    const int b    = bid >> 9;
    const int tid  = threadIdx.x;
    const int wid  = tid >> 6;
    const int lane = tid & 63;
    const int lo   = lane & 15;
    const int g    = lane >> 4;

    const size_t bh = (size_t)b * NHEADS + h;
    const int qbase = qt * 64 + wid * 16;

    const u16* qrowp = qb + (bh * SEQ + qbase + lo) * HDIM + 8 * g;
    const bf16x8 aq0 = *(const bf16x8*)(qrowp);
    const bf16x8 aq1 = *(const bf16x8*)(qrowp + 32);

    const int krow = tid >> 3, kseg = tid & 7;
    const int kidx = krow * 64 + ((kseg * 8) ^ ((krow & 7) << 3));
    const u16* kgp = kb + bh * SEQ * HDIM + (size_t)krow * HDIM + kseg * 8;
    const int vrow = tid >> 2, vseg = tid & 3;
    const int vidx = vrow * 32 + vseg * 8;
    const u16* vgp = vtb + (bh * HDIM + vrow) * SEQ + vseg * 8;

    int kf[2][2];
    #pragma unroll
    for (int kt = 0; kt < 2; ++kt) {
        int key = lo + 16 * kt;
        #pragma unroll
        for (int ks = 0; ks < 2; ++ks)
            kf[kt][ks] = key * 64 + ((ks * 32 + 8 * g) ^ ((key & 7) << 3));
    }

    f32x4 acc[4] = {};
    float mrun[4], lrun[4];
    #pragma unroll
    for (int r = 0; r < 4; ++r) { mrun[r] = -1e30f; lrun[r] = 0.f; }

    u16* pw = &Plds[wid][0];

    for (int k0 = 0; k0 < SEQ; k0 += 32) {
        __syncthreads();
        *(bf16x8*)&Ks[kidx] = *(const bf16x8*)(kgp + (size_t)k0 * HDIM);
        *(bf16x8*)&Vt[vidx] = *(const bf16x8*)(vgp + k0);
        if (tid < 32) Ms[tid] = mask[b * SEQ + k0 + tid];
        __syncthreads();

        f32x4 s0 = {}, s1 = {};
        s0 = __builtin_amdgcn_mfma_f32_16x16x32_bf16(aq0, *(const bf16x8*)&Ks[kf[0][0]], s0, 0, 0, 0);
        s0 = __builtin_amdgcn_mfma_f32_16x16x32_bf16(aq1, *(const bf16x8*)&Ks[kf[0][1]], s0, 0, 0, 0);
        s1 = __builtin_amdgcn_mfma_f32_16x16x32_bf16(aq0, *(const bf16x8*)&Ks[kf[1][0]], s1, 0, 0, 0);
        s1 = __builtin_amdgcn_mfma_f32_16x16x32_bf16(aq1, *(const bf16x8*)&Ks[kf[1][1]], s1, 0, 0, 0);

        float p0v[4], p1v[4];
        #pragma unroll
        for (int r = 0; r < 4; ++r) {
            float rm = fmaxf(s0[r], s1[r]);
            rm = fmaxf(rm, __shfl_xor(rm, 1));
            rm = fmaxf(rm, __shfl_xor(rm, 2));
            rm = fmaxf(rm, __shfl_xor(rm, 4));
            rm = fmaxf(rm, __shfl_xor(rm, 8));
            float mnew = fmaxf(mrun[r], rm);
            float corr = __expf(mrun[r] - mnew);
            mrun[r] = mnew;
            float p0 = __expf(s0[r] - mnew);
            float p1 = __expf(s1[r] - mnew);
            float ps = p0 + p1;                 // UNMASKED denominator
            ps += __shfl_xor(ps, 1);
            ps += __shfl_xor(ps, 2);
            ps += __shfl_xor(ps, 4);
            ps += __shfl_xor(ps, 8);
            lrun[r] = lrun[r] * corr + ps;
            #pragma unroll
            for (int dt = 0; dt < 4; ++dt) acc[dt][r] *= corr;
            p0v[r] = p0; p1v[r] = p1;
        }

        const float mv0 = Ms[lo], mv1 = Ms[lo + 16];
        #pragma unroll
        for (int r = 0; r < 4; ++r) {
            pw[(4 * g + r) * 40 + lo]      = f2bf(p0v[r] * mv0);
            pw[(4 * g + r) * 40 + lo + 16] = f2bf(p1v[r] * mv1);
        }

        const bf16x8 pa = *(const bf16x8*)&pw[lo * 40 + 8 * g];
        #pragma unroll
        for (int dt = 0; dt < 4; ++dt) {
            const bf16x8 bv = *(const bf16x8*)&Vt[(lo + 16 * dt) * 32 + 8 * g];
            acc[dt] = __builtin_amdgcn_mfma_f32_16x16x32_bf16(pa, bv, acc[dt], 0, 0, 0);
        }
    }

    #pragma unroll
    for (int r = 0; r < 4; ++r) {
        float inv = 1.f / lrun[r];
        size_t row = (size_t)b * SEQ + qbase + 4 * g + r;
        u16* dh = ohi + row * DIMC + h * HDIM + lo;
        u16* dl = olo + row * DIMC + h * HDIM + lo;
        #pragma unroll
        for (int dt = 0; dt < 4; ++dt) {
            float o = acc[dt][r] * inv;
            u16 hv = f2bf(o);
            dh[16 * dt] = hv;
            dl[16 * dt] = f2bf(o - bf2f(hv));
        }
    }
}

__global__ void mask_sqrt_kernel(const float* __restrict__ mask,
                                 float* __restrict__ out, int n)
{
    int i = blockIdx.x * 256 + threadIdx.x;
    if (i < n) out[i] = sqrtf(mask[i]);
}

// ---------------------------------------------------------------------------
extern "C" void kernel_launch(void* const* d_in, const int* in_sizes, int n_in,
                              void* d_out, int out_size, void* d_ws, size_t ws_size,
                              hipStream_t stream)
{
    const float* h      = (const float*)d_in[0];   // [2,2048,1024]
    const float* mask   = (const float*)d_in[1];   // [2,2048]
    const float* w_qkv  = (const float*)d_in[2];   // [1024,3072]
    const float* w_proj = (const float*)d_in[3];   // [1024,1024]
    const float* b_proj = (const float*)d_in[4];   // [1024]
    float* out = (float*)d_out;

    // ws layout (u16 units), ~59 MB total
    u16* w    = (u16*)d_ws;
    u16* qkv  = w;                                  // 3*BHND
    u16* wqh  = qkv + 3 * BHND;                     // 3072*1024
    u16* wql  = wqh + (size_t)3072 * 1024;
    u16* wph  = wql + (size_t)3072 * 1024;          // 1024*1024
    u16* wpl  = wph + (size_t)1024 * 1024;
    u16* ahi  = wpl + (size_t)1024 * 1024;          // 4096*1024 (h split; later O split)
    u16* alo  = ahi + MROWS * DIMC;

    // prepasses: split h; split+transpose weights
    splita_kernel<<<(MROWS * DIMC) / (256 * 8), 256, 0, stream>>>(h, ahi, alo);
    splitw_kernel<<<dim3(16, 48), 256, 0, stream>>>(w_qkv, wqh, wql, DIMC, 3 * DIMC);
    splitw_kernel<<<dim3(16, 16), 256, 0, stream>>>(w_proj, wph, wpl, DIMC, DIMC);

    // 1) qkv projection (split MFMA) -> bf16 q(scaled)/k [B][H][N][D], v^T [B][H][D][N]
    gemm_split_kernel<0><<<dim3(24, 32), 256, 0, stream>>>(
        ahi, alo, wqh, wql, nullptr, nullptr, qkv, MROWS, 3 * DIMC, DIMC);

    // 2) MFMA flash attention -> split O over the dead h-split buffers
    attn_mfma_kernel<<<BATCH * NHEADS * (SEQ / 64), 256, 0, stream>>>(
        qkv, qkv + BHND, qkv + 2 * BHND, mask, ahi, alo);

    // 3) output projection + bias (split MFMA, fp32 out)
    gemm_split_kernel<1><<<dim3(8, 32), 256, 0, stream>>>(
        ahi, alo, wph, wpl, b_proj, out, nullptr, MROWS, DIMC, DIMC);

    // 4) new_mask = sqrt(mask)
    mask_sqrt_kernel<<<(BATCH * SEQ + 255) / 256, 256, 0, stream>>>(
        mask, out + MROWS * DIMC, BATCH * SEQ);
}